// Round 22
// baseline (178.293 us; speedup 1.0000x reference)
//
#include <hip/hip_runtime.h>
#include <hip/hip_bf16.h>
#include <math.h>

#define N_NODES 50000
#define N_EDGES 800000
#define NB1 196  // ceil(50000/256)

typedef __attribute__((ext_vector_type(8))) short bf16x8;
typedef __attribute__((ext_vector_type(4))) float f32x4;
typedef __attribute__((ext_vector_type(2))) unsigned uint2v;
typedef __attribute__((ext_vector_type(4))) unsigned short us4;

// ---- bf16 helpers: native RNE conversion (compiles to v_cvt_pk_bf16_f32) ----
__device__ __forceinline__ unsigned short f2bf(float f) {
    union { __hip_bfloat16 b; unsigned short u; } cv;
    cv.b = __float2bfloat16(f);
    return cv.u;
}
__device__ __forceinline__ float bf2f(unsigned short u) {
    return __uint_as_float(((unsigned)u) << 16);
}
__device__ __forceinline__ unsigned pack2bf(float a, float b) {
    return (unsigned)f2bf(a) | ((unsigned)f2bf(b) << 16);
}
union BFU { bf16x8 v; unsigned u[4]; };

// Build ALL MFMA B-fragments (34 frags x 512 shorts) + zero degi.
__global__ __launch_bounds__(256) void kw_kernel(const float* __restrict__ We,
                                                 const float* __restrict__ Wa,
                                                 const float* __restrict__ Wn,
                                                 const float* __restrict__ W2,
                                                 short* __restrict__ Bpack,
                                                 int* __restrict__ degi) {
    int t = blockIdx.x * 256 + threadIdx.x;
    if (t < N_NODES) degi[t] = 0;
    if (t < 34 * 512) {
        int f = t >> 9, u = t & 511, lane = u >> 3, j = u & 7;
        int c = lane & 15, G = lane >> 4;
        float v = 0.f;
        if (f < 8) {
            int s = f >> 2, n = f & 3;
            int kp = 32 * s + 8 * G + j;
            #pragma unroll
            for (int kk = 0; kk < 32; ++kk)
                v += W2[(16 * n + c) * 96 + 64 + kk] * We[kk * 64 + kp];
        } else if (f < 10) {
            int s = f - 8;
            if (c == 0) {
                int kp = 32 * s + 8 * G + j;
                #pragma unroll
                for (int jj = 0; jj < 32; ++jj) v += Wa[64 + jj] * We[jj * 64 + kp];
            }
        } else if (f < 26) {
            int qf = f - 10, s = qf >> 2, n = qf & 3;
            v = Wn[(16 * n + c) * 128 + 32 * s + 8 * G + j];
        } else {
            int qf = f - 26, s = qf >> 2, n = qf & 3;
            v = W2[(16 * n + c) * 96 + 32 * s + 8 * G + j];
        }
        Bpack[t] = (short)f2bf(v);
    }
}

// ---- FUSED: node pass (MFMA, blocks [0,782)) + hist (blocks [782,3907)) ----
__global__ __launch_bounds__(256) void node_hist_kernel(
    const float* __restrict__ h, const float* __restrict__ Wa,
    const short* __restrict__ Bpack, const int* __restrict__ dst,
    float* __restrict__ z, ushort4* __restrict__ y16p,
    float* __restrict__ asrc, float* __restrict__ adst,
    int* __restrict__ degi, int* __restrict__ ranks)
{
    __shared__ float zl[4][1088];    // per-wave 16x68 transpose buffer
    int t = threadIdx.x;
    if (blockIdx.x >= 782) {
        int e = (blockIdx.x - 782) * 256 + t;
        if (e < N_EDGES) ranks[e] = atomicAdd(&degi[dst[e]], 1);
        return;
    }
    int w = t >> 6, l = t & 63, c = l & 15, G = l >> 4;
    int T = blockIdx.x * 4 + w;
    if (T >= 3125) return;           // no barriers in this kernel -> safe
    int n0 = T * 16;
    const bf16x8* Bp = (const bf16x8*)Bpack;

    const float* hp = h + (size_t)(n0 + c) * 128 + 8 * G;
    bf16x8 a[4];
    #pragma unroll
    for (int s = 0; s < 4; ++s) {
        float4 lo = *(const float4*)(hp + 32 * s);
        float4 hi = *(const float4*)(hp + 32 * s + 4);
        BFU ua;
        ua.u[0] = pack2bf(lo.x, lo.y);
        ua.u[1] = pack2bf(lo.z, lo.w);
        ua.u[2] = pack2bf(hi.x, hi.y);
        ua.u[3] = pack2bf(hi.z, hi.w);
        a[s] = ua.v;
    }
    f32x4 acc[4] = {{0.f,0.f,0.f,0.f},{0.f,0.f,0.f,0.f},{0.f,0.f,0.f,0.f},{0.f,0.f,0.f,0.f}};
    #pragma unroll
    for (int n = 0; n < 4; ++n)
        #pragma unroll
        for (int s = 0; s < 4; ++s)
            acc[n] = __builtin_amdgcn_mfma_f32_16x16x32_bf16(a[s], Bp[(10 + 4*s + n)*64 + l], acc[n], 0, 0, 0);

    float was[4], wad[4];
    #pragma unroll
    for (int n = 0; n < 4; ++n) { was[n] = Wa[16*n + c]; wad[n] = Wa[96 + 16*n + c]; }

    #pragma unroll
    for (int r = 0; r < 4; ++r) {
        int row = n0 + 4 * G + r;
        #pragma unroll
        for (int n = 0; n < 4; ++n) {
            z[(size_t)row * 64 + 16 * n + c] = acc[n][r];
            zl[w][(4 * G + r) * 68 + 16 * n + c] = acc[n][r];
        }
        float ps = acc[0][r]*was[0] + acc[1][r]*was[1] + acc[2][r]*was[2] + acc[3][r]*was[3];
        float pd = acc[0][r]*wad[0] + acc[1][r]*wad[1] + acc[2][r]*wad[2] + acc[3][r]*wad[3];
        ps += __shfl_xor(ps, 1); ps += __shfl_xor(ps, 2);
        ps += __shfl_xor(ps, 4); ps += __shfl_xor(ps, 8);
        pd += __shfl_xor(pd, 1); pd += __shfl_xor(pd, 2);
        pd += __shfl_xor(pd, 4); pd += __shfl_xor(pd, 8);
        if (c == 0) { asrc[row] = ps; adst[row] = pd; }
    }

    bf16x8 ay[2];
    #pragma unroll
    for (int s = 0; s < 2; ++s) {
        BFU ua;
        #pragma unroll
        for (int jp = 0; jp < 4; ++jp)
            ua.u[jp] = pack2bf(zl[w][c * 68 + 32 * s + 8 * G + 2 * jp],
                               zl[w][c * 68 + 32 * s + 8 * G + 2 * jp + 1]);
        ay[s] = ua.v;
    }
    f32x4 accy[4] = {{0.f,0.f,0.f,0.f},{0.f,0.f,0.f,0.f},{0.f,0.f,0.f,0.f},{0.f,0.f,0.f,0.f}};
    #pragma unroll
    for (int n = 0; n < 4; ++n)
        #pragma unroll
        for (int s = 0; s < 2; ++s)
            accy[n] = __builtin_amdgcn_mfma_f32_16x16x32_bf16(ay[s], Bp[(26 + 4*s + n)*64 + l], accy[n], 0, 0, 0);
    #pragma unroll
    for (int r = 0; r < 4; ++r) {
        ushort4 yo;
        yo.x = f2bf(accy[0][r]); yo.y = f2bf(accy[1][r]);
        yo.z = f2bf(accy[2][r]); yo.w = f2bf(accy[3][r]);
        y16p[(size_t)(n0 + 4 * G + r) * 16 + c] = yo;
    }
}

// ---- CSR scans (2 launches: block partials, then fused apply) ----
__global__ __launch_bounds__(256) void scan1_kernel(const int* __restrict__ degi,
                                                    int* __restrict__ partial) {
    int t = threadIdx.x, i = blockIdx.x * 256 + t;
    int d = (i < N_NODES) ? degi[i] : 0;
    #pragma unroll
    for (int off = 32; off; off >>= 1) d += __shfl_down(d, off);
    __shared__ int wsum[4];
    if ((t & 63) == 0) wsum[t >> 6] = d;
    __syncthreads();
    if (t == 0) partial[blockIdx.x] = wsum[0] + wsum[1] + wsum[2] + wsum[3];
}

// Each block redundantly scans the 196 partials in LDS for its exclusive
// base, then scans its own degi tile — fuses old scan2+scan3.
__global__ __launch_bounds__(256) void scan23_kernel(const int* __restrict__ degi,
                                                     const int* __restrict__ partial,
                                                     int* __restrict__ start) {
    __shared__ int s[256];
    int b = blockIdx.x, t = threadIdx.x;
    // phase 1: inclusive scan of block partials
    int v = (t < NB1) ? partial[t] : 0;
    s[t] = v; __syncthreads();
    for (int off = 1; off < 256; off <<= 1) {
        int x = (t >= off) ? s[t - off] : 0;
        __syncthreads();
        s[t] += x;
        __syncthreads();
    }
    int exc = (b == 0) ? 0 : s[b - 1];
    __syncthreads();
    // phase 2: scan this block's degi tile
    int i = b * 256 + t;
    int d = (i < N_NODES) ? degi[i] : 0;
    s[t] = d; __syncthreads();
    for (int off = 1; off < 256; off <<= 1) {
        int x = (t >= off) ? s[t - off] : 0;
        __syncthreads();
        s[t] += x;
        __syncthreads();
    }
    if (i < N_NODES) start[i] = exc + s[t] - d;
}

// ---- Edge pass: 64 edges/wave, 1-deep prefetch.
//      NONTEMPORAL on the no-reuse streams (ef read, wout write) so L2
//      stays resident for y16p/exslot/metadata. ----
__global__ __launch_bounds__(256, 2) void edge_kernel(
    const float* __restrict__ edge_feat, const int* __restrict__ src,
    const int* __restrict__ dst, const int* __restrict__ ranks,
    const int* __restrict__ start, const float* __restrict__ asrc,
    const float* __restrict__ adst, const short* __restrict__ Bpack,
    const ushort4* __restrict__ y16p,
    unsigned short* __restrict__ wout, float* __restrict__ exslot)
{
    int t = threadIdx.x, w = t >> 6, l = t & 63;
    int c = l & 15, G = l >> 4;
    int wbase = blockIdx.x * 256 + w * 64;   // grid exact: 3125*256 = 800000

    const bf16x8* Bp = (const bf16x8*)Bpack;
    bf16x8 bc[8];
    #pragma unroll
    for (int f = 0; f < 8; ++f) bc[f] = Bp[f * 64 + l];
    bf16x8 b2a = Bp[8 * 64 + l];
    bf16x8 b2b = Bp[9 * 64 + l];

    int e = wbase + l;
    int se = src[e];
    int de = dst[e];
    int slot = start[de] + ranks[e];
    float apre = asrc[se] + adst[de];

    const float* efr = edge_feat + (size_t)(wbase + c) * 64 + G * 8;
    f32x4 n0 = __builtin_nontemporal_load((const f32x4*)(efr));
    f32x4 n1 = __builtin_nontemporal_load((const f32x4*)(efr + 4));
    f32x4 n2 = __builtin_nontemporal_load((const f32x4*)(efr + 32));
    f32x4 n3 = __builtin_nontemporal_load((const f32x4*)(efr + 36));

    #pragma unroll
    for (int k = 0; k < 4; ++k) {
        f32x4 c0 = n0, c1 = n1, c2 = n2, c3 = n3;
        if (k < 3) {
            const float* efn = edge_feat + (size_t)(wbase + 16 * (k + 1) + c) * 64 + G * 8;
            n0 = __builtin_nontemporal_load((const f32x4*)(efn));
            n1 = __builtin_nontemporal_load((const f32x4*)(efn + 4));
            n2 = __builtin_nontemporal_load((const f32x4*)(efn + 32));
            n3 = __builtin_nontemporal_load((const f32x4*)(efn + 36));
        }
        // per-edge meta for this batch's 4 group-edges; issue y-gathers early
        int sr[4], sl4[4]; float ap[4];
        #pragma unroll
        for (int r = 0; r < 4; ++r) {
            int si = 16 * k + 4 * G + r;
            sr[r]  = __shfl(se, si);
            sl4[r] = __shfl(slot, si);
            ap[r]  = __shfl(apre, si);
        }
        ushort4 yv[4];
        #pragma unroll
        for (int r = 0; r < 4; ++r) yv[r] = y16p[(size_t)sr[r] * 16 + c];

        BFU ua0, ua1;
        ua0.u[0] = pack2bf(c0[0], c0[1]);
        ua0.u[1] = pack2bf(c0[2], c0[3]);
        ua0.u[2] = pack2bf(c1[0], c1[1]);
        ua0.u[3] = pack2bf(c1[2], c1[3]);
        ua1.u[0] = pack2bf(c2[0], c2[1]);
        ua1.u[1] = pack2bf(c2[2], c2[3]);
        ua1.u[2] = pack2bf(c3[0], c3[1]);
        ua1.u[3] = pack2bf(c3[2], c3[3]);
        bf16x8 a0 = ua0.v, a1 = ua1.v;

        f32x4 acc[4] = {{0.f,0.f,0.f,0.f},{0.f,0.f,0.f,0.f},{0.f,0.f,0.f,0.f},{0.f,0.f,0.f,0.f}};
        f32x4 acc2 = {0.f, 0.f, 0.f, 0.f};
        #pragma unroll
        for (int n = 0; n < 4; ++n) {
            acc[n] = __builtin_amdgcn_mfma_f32_16x16x32_bf16(a0, bc[n], acc[n], 0, 0, 0);
            acc[n] = __builtin_amdgcn_mfma_f32_16x16x32_bf16(a1, bc[4 + n], acc[n], 0, 0, 0);
        }
        acc2 = __builtin_amdgcn_mfma_f32_16x16x32_bf16(a0, b2a, acc2, 0, 0, 0);
        acc2 = __builtin_amdgcn_mfma_f32_16x16x32_bf16(a1, b2b, acc2, 0, 0, 0);

        #pragma unroll
        for (int r = 0; r < 4; ++r) {
            float u0 = acc[0][r] + bf2f(yv[r].x);
            float u1 = acc[1][r] + bf2f(yv[r].y);
            float u2 = acc[2][r] + bf2f(yv[r].z);
            float u3 = acc[3][r] + bf2f(yv[r].w);
            uint2v o;
            o[0] = pack2bf(u0, u1);
            o[1] = pack2bf(u2, u3);
            // full 128B line per slot, 16 lanes x 8B, no RMW; NT: no reuse
            __builtin_nontemporal_store(o, (uint2v*)&wout[(size_t)sl4[r] * 64 + 4 * c]);
            if (c == 0) {
                float aa = ap[r] + acc2[r];
                float sg = aa > 0.f ? aa : 0.01f * aa;
                exslot[sl4[r]] = __expf(sg);   // segmax shift mathematically redundant
            }
        }
    }
}

// ---- Pass B: PURE STREAMING segmented sum, 16 slots/iteration, NT loads. ----
__global__ __launch_bounds__(256) void agg_kernel(
    const ushort4* __restrict__ wout4, const float* __restrict__ exslot,
    const int* __restrict__ start, const int* __restrict__ degi,
    const float* __restrict__ z, float* __restrict__ out)
{
    int t = threadIdx.x, w = t >> 6, l = t & 63, c = l & 15, g = l >> 4;
    int d    = blockIdx.x * 4 + w;           // grid exact: 12500*4 = 50000
    int base = __builtin_amdgcn_readfirstlane(start[d]);
    int deg  = __builtin_amdgcn_readfirstlane(degi[d]);

    float4 acc = make_float4(0.f, 0.f, 0.f, 0.f);
    float den = 0.f;
    for (int i = 0; i < deg; i += 16) {
        int ix[4]; bool vv[4]; int kk[4];
        float xs[4];
        #pragma unroll
        for (int q4 = 0; q4 < 4; ++q4) {
            ix[q4] = i + 4 * q4 + g;
            vv[q4] = ix[q4] < deg;
            kk[q4] = vv[q4] ? ix[q4] : 0;      // clamped: in-bounds (deg>0 here)
        }
        us4 ua = __builtin_nontemporal_load((const us4*)(wout4 + (size_t)(base + kk[0]) * 16 + c));
        us4 ub = __builtin_nontemporal_load((const us4*)(wout4 + (size_t)(base + kk[1]) * 16 + c));
        us4 uc = __builtin_nontemporal_load((const us4*)(wout4 + (size_t)(base + kk[2]) * 16 + c));
        us4 ud = __builtin_nontemporal_load((const us4*)(wout4 + (size_t)(base + kk[3]) * 16 + c));
        #pragma unroll
        for (int q4 = 0; q4 < 4; ++q4)
            xs[q4] = vv[q4] ? exslot[base + ix[q4]] : 0.f;

        acc.x += xs[0] * bf2f(ua[0]); acc.y += xs[0] * bf2f(ua[1]);
        acc.z += xs[0] * bf2f(ua[2]); acc.w += xs[0] * bf2f(ua[3]);
        den += xs[0];
        acc.x += xs[1] * bf2f(ub[0]); acc.y += xs[1] * bf2f(ub[1]);
        acc.z += xs[1] * bf2f(ub[2]); acc.w += xs[1] * bf2f(ub[3]);
        den += xs[1];
        acc.x += xs[2] * bf2f(uc[0]); acc.y += xs[2] * bf2f(uc[1]);
        acc.z += xs[2] * bf2f(uc[2]); acc.w += xs[2] * bf2f(uc[3]);
        den += xs[2];
        acc.x += xs[3] * bf2f(ud[0]); acc.y += xs[3] * bf2f(ud[1]);
        acc.z += xs[3] * bf2f(ud[2]); acc.w += xs[3] * bf2f(ud[3]);
        den += xs[3];
    }

    // combine 4 slot-groups
    acc.x += __shfl_xor(acc.x, 16); acc.x += __shfl_xor(acc.x, 32);
    acc.y += __shfl_xor(acc.y, 16); acc.y += __shfl_xor(acc.y, 32);
    acc.z += __shfl_xor(acc.z, 16); acc.z += __shfl_xor(acc.z, 32);
    acc.w += __shfl_xor(acc.w, 16); acc.w += __shfl_xor(acc.w, 32);
    den += __shfl_xor(den, 16); den += __shfl_xor(den, 32);

    if (g == 0) {   // 16 lanes write 4 comps each (comp = 16*j + c)
        size_t ob = (size_t)d * 64;
        if (deg > 0) {
            float inv = 1.f / den;
            out[ob + c]      = acc.x * inv;
            out[ob + 16 + c] = acc.y * inv;
            out[ob + 32 + c] = acc.z * inv;
            out[ob + 48 + c] = acc.w * inv;
        } else {
            out[ob + c]      = z[ob + c];
            out[ob + 16 + c] = z[ob + 16 + c];
            out[ob + 32 + c] = z[ob + 32 + c];
            out[ob + 48 + c] = z[ob + 48 + c];
        }
    }
}

extern "C" void kernel_launch(void* const* d_in, const int* in_sizes, int n_in,
                              void* d_out, int out_size, void* d_ws, size_t ws_size,
                              hipStream_t stream) {
    const float* h         = (const float*)d_in[0];
    const float* edge_feat = (const float*)d_in[1];
    const int*   src       = (const int*)d_in[2];
    const int*   dst       = (const int*)d_in[3];
    const float* Wn        = (const float*)d_in[4];
    const float* We        = (const float*)d_in[5];
    const float* Wa        = (const float*)d_in[6];
    const float* W2        = (const float*)d_in[7];
    float* out = (float*)d_out;

    char* p = (char*)d_ws;
    // wout FIRST: keeps 128B line alignment for the full-line scatter
    unsigned short* wout   = (unsigned short*)p; p += (size_t)N_EDGES * 64 * 2;   // 102.4 MB
    float*          z      = (float*)p;          p += (size_t)N_NODES * 64 * 4;   // 12.8 MB
    ushort4*        y16p   = (ushort4*)p;        p += (size_t)N_NODES * 64 * 2;   // 6.4 MB
    float*          exslot = (float*)p;          p += (size_t)N_EDGES * 4;        // 3.2 MB
    float*          asrc   = (float*)p;          p += (size_t)N_NODES * 4;
    float*          adst   = (float*)p;          p += (size_t)N_NODES * 4;
    int*            degi   = (int*)p;            p += (size_t)N_NODES * 4;
    int*            start  = (int*)p;            p += (size_t)N_NODES * 4;
    int*            ranks  = (int*)p;            p += (size_t)N_EDGES * 4;        // 3.2 MB
    int*            partial= (int*)p;            p += (size_t)256 * 4;
    short*          Bpack  = (short*)p;          p += (size_t)34 * 512 * 2;       // 35 KB

    kw_kernel<<<NB1, 256, 0, stream>>>(We, Wa, Wn, W2, Bpack, degi);
    node_hist_kernel<<<782 + 3125, 256, 0, stream>>>(h, Wa, Bpack, dst, z, y16p,
                                                     asrc, adst, degi, ranks);
    scan1_kernel<<<NB1, 256, 0, stream>>>(degi, partial);
    scan23_kernel<<<NB1, 256, 0, stream>>>(degi, partial, start);
    edge_kernel<<<3125, 256, 0, stream>>>(edge_feat, src, dst, ranks, start,
                                          asrc, adst, Bpack, y16p, wout, exslot);
    agg_kernel<<<N_NODES / 4, 256, 0, stream>>>((const ushort4*)wout, exslot,
                                                start, degi, z, out);
}

// Round 23
// 165.327 us; speedup vs baseline: 1.0784x; 1.0784x over previous
//
#include <hip/hip_runtime.h>
#include <hip/hip_bf16.h>
#include <math.h>

#define N_NODES 50000
#define N_EDGES 800000
#define NB1 196  // ceil(50000/256)

typedef __attribute__((ext_vector_type(8))) short bf16x8;
typedef __attribute__((ext_vector_type(4))) float f32x4;

// ---- bf16 helpers: native RNE conversion (compiles to v_cvt_pk_bf16_f32) ----
__device__ __forceinline__ unsigned short f2bf(float f) {
    union { __hip_bfloat16 b; unsigned short u; } cv;
    cv.b = __float2bfloat16(f);
    return cv.u;
}
__device__ __forceinline__ float bf2f(unsigned short u) {
    return __uint_as_float(((unsigned)u) << 16);
}
__device__ __forceinline__ unsigned pack2bf(float a, float b) {
    return (unsigned)f2bf(a) | ((unsigned)f2bf(b) << 16);
}
union BFU { bf16x8 v; unsigned u[4]; };

// Build ALL MFMA B-fragments (34 frags x 512 shorts) + zero degi.
__global__ __launch_bounds__(256) void kw_kernel(const float* __restrict__ We,
                                                 const float* __restrict__ Wa,
                                                 const float* __restrict__ Wn,
                                                 const float* __restrict__ W2,
                                                 short* __restrict__ Bpack,
                                                 int* __restrict__ degi) {
    int t = blockIdx.x * 256 + threadIdx.x;
    if (t < N_NODES) degi[t] = 0;
    if (t < 34 * 512) {
        int f = t >> 9, u = t & 511, lane = u >> 3, j = u & 7;
        int c = lane & 15, G = lane >> 4;
        float v = 0.f;
        if (f < 8) {
            int s = f >> 2, n = f & 3;
            int kp = 32 * s + 8 * G + j;
            #pragma unroll
            for (int kk = 0; kk < 32; ++kk)
                v += W2[(16 * n + c) * 96 + 64 + kk] * We[kk * 64 + kp];
        } else if (f < 10) {
            int s = f - 8;
            if (c == 0) {
                int kp = 32 * s + 8 * G + j;
                #pragma unroll
                for (int jj = 0; jj < 32; ++jj) v += Wa[64 + jj] * We[jj * 64 + kp];
            }
        } else if (f < 26) {
            int qf = f - 10, s = qf >> 2, n = qf & 3;
            v = Wn[(16 * n + c) * 128 + 32 * s + 8 * G + j];
        } else {
            int qf = f - 26, s = qf >> 2, n = qf & 3;
            v = W2[(16 * n + c) * 96 + 32 * s + 8 * G + j];
        }
        Bpack[t] = (short)f2bf(v);
    }
}

// ---- FUSED: node pass (MFMA, blocks [0,782)) + hist (blocks [782,3907)) ----
__global__ __launch_bounds__(256) void node_hist_kernel(
    const float* __restrict__ h, const float* __restrict__ Wa,
    const short* __restrict__ Bpack, const int* __restrict__ dst,
    float* __restrict__ z, ushort4* __restrict__ y16p,
    float* __restrict__ asrc, float* __restrict__ adst,
    int* __restrict__ degi, int* __restrict__ ranks)
{
    __shared__ float zl[4][1088];    // per-wave 16x68 transpose buffer
    int t = threadIdx.x;
    if (blockIdx.x >= 782) {
        int e = (blockIdx.x - 782) * 256 + t;
        if (e < N_EDGES) ranks[e] = atomicAdd(&degi[dst[e]], 1);
        return;
    }
    int w = t >> 6, l = t & 63, c = l & 15, G = l >> 4;
    int T = blockIdx.x * 4 + w;
    if (T >= 3125) return;           // no barriers in this kernel -> safe
    int n0 = T * 16;
    const bf16x8* Bp = (const bf16x8*)Bpack;

    const float* hp = h + (size_t)(n0 + c) * 128 + 8 * G;
    bf16x8 a[4];
    #pragma unroll
    for (int s = 0; s < 4; ++s) {
        float4 lo = *(const float4*)(hp + 32 * s);
        float4 hi = *(const float4*)(hp + 32 * s + 4);
        BFU ua;
        ua.u[0] = pack2bf(lo.x, lo.y);
        ua.u[1] = pack2bf(lo.z, lo.w);
        ua.u[2] = pack2bf(hi.x, hi.y);
        ua.u[3] = pack2bf(hi.z, hi.w);
        a[s] = ua.v;
    }
    f32x4 acc[4] = {{0.f,0.f,0.f,0.f},{0.f,0.f,0.f,0.f},{0.f,0.f,0.f,0.f},{0.f,0.f,0.f,0.f}};
    #pragma unroll
    for (int n = 0; n < 4; ++n)
        #pragma unroll
        for (int s = 0; s < 4; ++s)
            acc[n] = __builtin_amdgcn_mfma_f32_16x16x32_bf16(a[s], Bp[(10 + 4*s + n)*64 + l], acc[n], 0, 0, 0);

    float was[4], wad[4];
    #pragma unroll
    for (int n = 0; n < 4; ++n) { was[n] = Wa[16*n + c]; wad[n] = Wa[96 + 16*n + c]; }

    #pragma unroll
    for (int r = 0; r < 4; ++r) {
        int row = n0 + 4 * G + r;
        #pragma unroll
        for (int n = 0; n < 4; ++n) {
            z[(size_t)row * 64 + 16 * n + c] = acc[n][r];
            zl[w][(4 * G + r) * 68 + 16 * n + c] = acc[n][r];
        }
        float ps = acc[0][r]*was[0] + acc[1][r]*was[1] + acc[2][r]*was[2] + acc[3][r]*was[3];
        float pd = acc[0][r]*wad[0] + acc[1][r]*wad[1] + acc[2][r]*wad[2] + acc[3][r]*wad[3];
        ps += __shfl_xor(ps, 1); ps += __shfl_xor(ps, 2);
        ps += __shfl_xor(ps, 4); ps += __shfl_xor(ps, 8);
        pd += __shfl_xor(pd, 1); pd += __shfl_xor(pd, 2);
        pd += __shfl_xor(pd, 4); pd += __shfl_xor(pd, 8);
        if (c == 0) { asrc[row] = ps; adst[row] = pd; }
    }

    bf16x8 ay[2];
    #pragma unroll
    for (int s = 0; s < 2; ++s) {
        BFU ua;
        #pragma unroll
        for (int jp = 0; jp < 4; ++jp)
            ua.u[jp] = pack2bf(zl[w][c * 68 + 32 * s + 8 * G + 2 * jp],
                               zl[w][c * 68 + 32 * s + 8 * G + 2 * jp + 1]);
        ay[s] = ua.v;
    }
    f32x4 accy[4] = {{0.f,0.f,0.f,0.f},{0.f,0.f,0.f,0.f},{0.f,0.f,0.f,0.f},{0.f,0.f,0.f,0.f}};
    #pragma unroll
    for (int n = 0; n < 4; ++n)
        #pragma unroll
        for (int s = 0; s < 2; ++s)
            accy[n] = __builtin_amdgcn_mfma_f32_16x16x32_bf16(ay[s], Bp[(26 + 4*s + n)*64 + l], accy[n], 0, 0, 0);
    #pragma unroll
    for (int r = 0; r < 4; ++r) {
        ushort4 yo;
        yo.x = f2bf(accy[0][r]); yo.y = f2bf(accy[1][r]);
        yo.z = f2bf(accy[2][r]); yo.w = f2bf(accy[3][r]);
        y16p[(size_t)(n0 + 4 * G + r) * 16 + c] = yo;
    }
}

// ---- CSR scans (2 launches: block partials, then fused apply) ----
__global__ __launch_bounds__(256) void scan1_kernel(const int* __restrict__ degi,
                                                    int* __restrict__ partial) {
    int t = threadIdx.x, i = blockIdx.x * 256 + t;
    int d = (i < N_NODES) ? degi[i] : 0;
    #pragma unroll
    for (int off = 32; off; off >>= 1) d += __shfl_down(d, off);
    __shared__ int wsum[4];
    if ((t & 63) == 0) wsum[t >> 6] = d;
    __syncthreads();
    if (t == 0) partial[blockIdx.x] = wsum[0] + wsum[1] + wsum[2] + wsum[3];
}

// Each block redundantly scans the 196 partials in LDS for its exclusive
// base, then scans its own degi tile — fuses old scan2+scan3.
__global__ __launch_bounds__(256) void scan23_kernel(const int* __restrict__ degi,
                                                     const int* __restrict__ partial,
                                                     int* __restrict__ start) {
    __shared__ int s[256];
    int b = blockIdx.x, t = threadIdx.x;
    // phase 1: inclusive scan of block partials
    int v = (t < NB1) ? partial[t] : 0;
    s[t] = v; __syncthreads();
    for (int off = 1; off < 256; off <<= 1) {
        int x = (t >= off) ? s[t - off] : 0;
        __syncthreads();
        s[t] += x;
        __syncthreads();
    }
    int exc = (b == 0) ? 0 : s[b - 1];
    __syncthreads();
    // phase 2: scan this block's degi tile
    int i = b * 256 + t;
    int d = (i < N_NODES) ? degi[i] : 0;
    s[t] = d; __syncthreads();
    for (int off = 1; off < 256; off <<= 1) {
        int x = (t >= off) ? s[t - off] : 0;
        __syncthreads();
        s[t] += x;
        __syncthreads();
    }
    if (i < N_NODES) start[i] = exc + s[t] - d;
}

// ---- Edge pass: 64 edges/wave, 1-deep prefetch.
//      Stream edge_feat; MFMA q = ef@Wc^T; u = q + y16p[src];
//      scatter bf16(u) to CSR slot as ONE FULL 128B line + 4B ex scatter. ----
__global__ __launch_bounds__(256, 2) void edge_kernel(
    const float* __restrict__ edge_feat, const int* __restrict__ src,
    const int* __restrict__ dst, const int* __restrict__ ranks,
    const int* __restrict__ start, const float* __restrict__ asrc,
    const float* __restrict__ adst, const short* __restrict__ Bpack,
    const ushort4* __restrict__ y16p,
    unsigned short* __restrict__ wout, float* __restrict__ exslot)
{
    int t = threadIdx.x, w = t >> 6, l = t & 63;
    int c = l & 15, G = l >> 4;
    int wbase = blockIdx.x * 256 + w * 64;   // grid exact: 3125*256 = 800000

    const bf16x8* Bp = (const bf16x8*)Bpack;
    bf16x8 bc[8];
    #pragma unroll
    for (int f = 0; f < 8; ++f) bc[f] = Bp[f * 64 + l];
    bf16x8 b2a = Bp[8 * 64 + l];
    bf16x8 b2b = Bp[9 * 64 + l];

    int e = wbase + l;
    int se = src[e];
    int de = dst[e];
    int slot = start[de] + ranks[e];
    float apre = asrc[se] + adst[de];

    const float* efr = edge_feat + (size_t)(wbase + c) * 64 + G * 8;
    float4 n0 = *(const float4*)(efr);
    float4 n1 = *(const float4*)(efr + 4);
    float4 n2 = *(const float4*)(efr + 32);
    float4 n3 = *(const float4*)(efr + 36);

    #pragma unroll
    for (int k = 0; k < 4; ++k) {
        float4 c0 = n0, c1 = n1, c2 = n2, c3 = n3;
        if (k < 3) {
            const float* efn = edge_feat + (size_t)(wbase + 16 * (k + 1) + c) * 64 + G * 8;
            n0 = *(const float4*)(efn);
            n1 = *(const float4*)(efn + 4);
            n2 = *(const float4*)(efn + 32);
            n3 = *(const float4*)(efn + 36);
        }
        // per-edge meta for this batch's 4 group-edges; issue y-gathers early
        int sr[4], sl4[4]; float ap[4];
        #pragma unroll
        for (int r = 0; r < 4; ++r) {
            int si = 16 * k + 4 * G + r;
            sr[r]  = __shfl(se, si);
            sl4[r] = __shfl(slot, si);
            ap[r]  = __shfl(apre, si);
        }
        ushort4 yv[4];
        #pragma unroll
        for (int r = 0; r < 4; ++r) yv[r] = y16p[(size_t)sr[r] * 16 + c];

        BFU ua0, ua1;
        ua0.u[0] = pack2bf(c0.x, c0.y);
        ua0.u[1] = pack2bf(c0.z, c0.w);
        ua0.u[2] = pack2bf(c1.x, c1.y);
        ua0.u[3] = pack2bf(c1.z, c1.w);
        ua1.u[0] = pack2bf(c2.x, c2.y);
        ua1.u[1] = pack2bf(c2.z, c2.w);
        ua1.u[2] = pack2bf(c3.x, c3.y);
        ua1.u[3] = pack2bf(c3.z, c3.w);
        bf16x8 a0 = ua0.v, a1 = ua1.v;

        f32x4 acc[4] = {{0.f,0.f,0.f,0.f},{0.f,0.f,0.f,0.f},{0.f,0.f,0.f,0.f},{0.f,0.f,0.f,0.f}};
        f32x4 acc2 = {0.f, 0.f, 0.f, 0.f};
        #pragma unroll
        for (int n = 0; n < 4; ++n) {
            acc[n] = __builtin_amdgcn_mfma_f32_16x16x32_bf16(a0, bc[n], acc[n], 0, 0, 0);
            acc[n] = __builtin_amdgcn_mfma_f32_16x16x32_bf16(a1, bc[4 + n], acc[n], 0, 0, 0);
        }
        acc2 = __builtin_amdgcn_mfma_f32_16x16x32_bf16(a0, b2a, acc2, 0, 0, 0);
        acc2 = __builtin_amdgcn_mfma_f32_16x16x32_bf16(a1, b2b, acc2, 0, 0, 0);

        #pragma unroll
        for (int r = 0; r < 4; ++r) {
            float u0 = acc[0][r] + bf2f(yv[r].x);
            float u1 = acc[1][r] + bf2f(yv[r].y);
            float u2 = acc[2][r] + bf2f(yv[r].z);
            float u3 = acc[3][r] + bf2f(yv[r].w);
            uint2 o;
            o.x = pack2bf(u0, u1);
            o.y = pack2bf(u2, u3);
            // full 128B line per slot, 16 lanes x 8B, no RMW
            *(uint2*)&wout[(size_t)sl4[r] * 64 + 4 * c] = o;
            if (c == 0) {
                float aa = ap[r] + acc2[r];
                float sg = aa > 0.f ? aa : 0.01f * aa;
                exslot[sl4[r]] = __expf(sg);   // segmax shift mathematically redundant
            }
        }
    }
}

// ---- Pass B: PURE STREAMING segmented sum, 16 slots/iteration. ----
__global__ __launch_bounds__(256) void agg_kernel(
    const ushort4* __restrict__ wout4, const float* __restrict__ exslot,
    const int* __restrict__ start, const int* __restrict__ degi,
    const float* __restrict__ z, float* __restrict__ out)
{
    int t = threadIdx.x, w = t >> 6, l = t & 63, c = l & 15, g = l >> 4;
    int d    = blockIdx.x * 4 + w;           // grid exact: 12500*4 = 50000
    int base = __builtin_amdgcn_readfirstlane(start[d]);
    int deg  = __builtin_amdgcn_readfirstlane(degi[d]);

    float4 acc = make_float4(0.f, 0.f, 0.f, 0.f);
    float den = 0.f;
    for (int i = 0; i < deg; i += 16) {
        int ix[4]; bool vv[4]; int kk[4];
        float xs[4];
        #pragma unroll
        for (int q4 = 0; q4 < 4; ++q4) {
            ix[q4] = i + 4 * q4 + g;
            vv[q4] = ix[q4] < deg;
            kk[q4] = vv[q4] ? ix[q4] : 0;      // clamped: in-bounds (deg>0 here)
        }
        ushort4 ua = wout4[(size_t)(base + kk[0]) * 16 + c];
        ushort4 ub = wout4[(size_t)(base + kk[1]) * 16 + c];
        ushort4 uc = wout4[(size_t)(base + kk[2]) * 16 + c];
        ushort4 ud = wout4[(size_t)(base + kk[3]) * 16 + c];
        #pragma unroll
        for (int q4 = 0; q4 < 4; ++q4)
            xs[q4] = vv[q4] ? exslot[base + ix[q4]] : 0.f;

        acc.x += xs[0] * bf2f(ua.x); acc.y += xs[0] * bf2f(ua.y);
        acc.z += xs[0] * bf2f(ua.z); acc.w += xs[0] * bf2f(ua.w);
        den += xs[0];
        acc.x += xs[1] * bf2f(ub.x); acc.y += xs[1] * bf2f(ub.y);
        acc.z += xs[1] * bf2f(ub.z); acc.w += xs[1] * bf2f(ub.w);
        den += xs[1];
        acc.x += xs[2] * bf2f(uc.x); acc.y += xs[2] * bf2f(uc.y);
        acc.z += xs[2] * bf2f(uc.z); acc.w += xs[2] * bf2f(uc.w);
        den += xs[2];
        acc.x += xs[3] * bf2f(ud.x); acc.y += xs[3] * bf2f(ud.y);
        acc.z += xs[3] * bf2f(ud.z); acc.w += xs[3] * bf2f(ud.w);
        den += xs[3];
    }

    // combine 4 slot-groups
    acc.x += __shfl_xor(acc.x, 16); acc.x += __shfl_xor(acc.x, 32);
    acc.y += __shfl_xor(acc.y, 16); acc.y += __shfl_xor(acc.y, 32);
    acc.z += __shfl_xor(acc.z, 16); acc.z += __shfl_xor(acc.z, 32);
    acc.w += __shfl_xor(acc.w, 16); acc.w += __shfl_xor(acc.w, 32);
    den += __shfl_xor(den, 16); den += __shfl_xor(den, 32);

    if (g == 0) {   // 16 lanes write 4 comps each (comp = 16*j + c)
        size_t ob = (size_t)d * 64;
        if (deg > 0) {
            float inv = 1.f / den;
            out[ob + c]      = acc.x * inv;
            out[ob + 16 + c] = acc.y * inv;
            out[ob + 32 + c] = acc.z * inv;
            out[ob + 48 + c] = acc.w * inv;
        } else {
            out[ob + c]      = z[ob + c];
            out[ob + 16 + c] = z[ob + 16 + c];
            out[ob + 32 + c] = z[ob + 32 + c];
            out[ob + 48 + c] = z[ob + 48 + c];
        }
    }
}

extern "C" void kernel_launch(void* const* d_in, const int* in_sizes, int n_in,
                              void* d_out, int out_size, void* d_ws, size_t ws_size,
                              hipStream_t stream) {
    const float* h         = (const float*)d_in[0];
    const float* edge_feat = (const float*)d_in[1];
    const int*   src       = (const int*)d_in[2];
    const int*   dst       = (const int*)d_in[3];
    const float* Wn        = (const float*)d_in[4];
    const float* We        = (const float*)d_in[5];
    const float* Wa        = (const float*)d_in[6];
    const float* W2        = (const float*)d_in[7];
    float* out = (float*)d_out;

    char* p = (char*)d_ws;
    // wout FIRST: keeps 128B line alignment for the full-line scatter
    unsigned short* wout   = (unsigned short*)p; p += (size_t)N_EDGES * 64 * 2;   // 102.4 MB
    float*          z      = (float*)p;          p += (size_t)N_NODES * 64 * 4;   // 12.8 MB
    ushort4*        y16p   = (ushort4*)p;        p += (size_t)N_NODES * 64 * 2;   // 6.4 MB
    float*          exslot = (float*)p;          p += (size_t)N_EDGES * 4;        // 3.2 MB
    float*          asrc   = (float*)p;          p += (size_t)N_NODES * 4;
    float*          adst   = (float*)p;          p += (size_t)N_NODES * 4;
    int*            degi   = (int*)p;            p += (size_t)N_NODES * 4;
    int*            start  = (int*)p;            p += (size_t)N_NODES * 4;
    int*            ranks  = (int*)p;            p += (size_t)N_EDGES * 4;        // 3.2 MB
    int*            partial= (int*)p;            p += (size_t)256 * 4;
    short*          Bpack  = (short*)p;          p += (size_t)34 * 512 * 2;       // 35 KB

    kw_kernel<<<NB1, 256, 0, stream>>>(We, Wa, Wn, W2, Bpack, degi);
    node_hist_kernel<<<782 + 3125, 256, 0, stream>>>(h, Wa, Bpack, dst, z, y16p,
                                                     asrc, adst, degi, ranks);
    scan1_kernel<<<NB1, 256, 0, stream>>>(degi, partial);
    scan23_kernel<<<NB1, 256, 0, stream>>>(degi, partial, start);
    edge_kernel<<<3125, 256, 0, stream>>>(edge_feat, src, dst, ranks, start,
                                          asrc, adst, Bpack, y16p, wout, exslot);
    agg_kernel<<<N_NODES / 4, 256, 0, stream>>>((const ushort4*)wout, exslot,
                                                start, degi, z, out);
}